// Round 16
// baseline (240.417 us; speedup 1.0000x reference)
//
#include <hip/hip_runtime.h>
#include <hip/hip_bf16.h>
#include <math.h>

#define B_ 8
#define P_ 24
#define N_ 1024
#define C_ 16
#define D_ 256
#define K_ 13

// workspace offsets (floats)
#define OFF_SMP  0          // sm partials [b][t][chunk4][16] = 12288
#define OFF_DLP  12288      // lag partials [b*4+li][t]*4+chunk = 3072
#define OFF_GAM  15552      // gamma: 8*32
#define OFF_PER  16384      // periodic [24][128] = 3072
#define OFF_C1PER 19456     // c1_per [13][256] = 3328
#define OFF_ZWC  22784      // zwc [8][256] = 2048
#define OFF_C1   24832      // c1 [b][k][256] = 26624
#define OFF_BC   51456      // bias_comb [13][256] = 3328
#define OFF_G    54784      // G [k][m][2][256] fp32 = 106496
#define OFF_AB   161280     // ABt bf16 fragment order = 53248 fl
#define OFF_ABP  214528     // AB partials fp32 = 851968
#define OFF_DD   1066496    // Dt bf16 fragment order = 425984 fl
#define OFF_W2E  1492480    // W2ext bf16 = 36864 fl
#define OFF_XC   1529344    // Xhat bf16 fragment order = 1703936 fl
#define OFF_XW   3233280    // xw fp32 = 131072
#define OFF_PACC 3364352    // GEMM1 split-k partials fp32 = 4194304

typedef unsigned short ushort_t;
typedef __bf16 bf16x8 __attribute__((ext_vector_type(8)));
typedef float f32x4 __attribute__((ext_vector_type(4)));
typedef unsigned short ushort4_t __attribute__((ext_vector_type(4)));

__device__ __forceinline__ float gelu_f(float v) {
    return 0.5f * v * (1.0f + erff(v * 0.70710678118654752440f));
}
__device__ __forceinline__ float softplus_f(float z) {
    return fmaxf(z, 0.0f) + log1pf(expf(-fabsf(z)));
}
__device__ __forceinline__ ushort_t f2bf(float f) {
    union { float f; unsigned u; } v; v.f = f;
    unsigned r = v.u + 0x7fffu + ((v.u >> 16) & 1u);
    return (ushort_t)(r >> 16);
}
__device__ __forceinline__ float bf2f(ushort_t h) {
    union { unsigned u; float f; } v; v.u = ((unsigned)h) << 16;
    return v.f;
}
__device__ __forceinline__ float4 f4add(float4 a, float4 b) {
    a.x += b.x; a.y += b.y; a.z += b.z; a.w += b.w; return a;
}
__device__ __forceinline__ ushort4_t pack4(f32x4 v, float4 c) {
    ushort4_t w;
    w.x = f2bf(gelu_f(v[0] + c.x));
    w.y = f2bf(gelu_f(v[1] + c.y));
    w.z = f2bf(gelu_f(v[2] + c.z));
    w.w = f2bf(gelu_f(v[3] + c.w));
    return w;
}
__device__ __forceinline__ ushort4_t pack4f(float4 v, float4 c) {
    ushort4_t w;
    w.x = f2bf(gelu_f(v.x + c.x));
    w.y = f2bf(gelu_f(v.y + c.y));
    w.z = f2bf(gelu_f(v.z + c.z));
    w.w = f2bf(gelu_f(v.w + c.w));
    return w;
}
__device__ __forceinline__ void lag_one(const float* xs, int t,
        float& s1, float& s2, float& s4, float& s6) {
    float xr[7];
    #pragma unroll
    for (int jj = 0; jj < 7; jj++) {
        int s = t - jj;
        float xt = xs[jj];
        xr[jj] = (s <= 0) ? 0.f
               : (s == 1) ? (xt - xs[jj + 1])
               : (xt - (xt + xs[jj + 1] + xs[jj + 2]) * (1.0f / 3.0f));
    }
    if (t >= 1) s1 += fabsf(xr[0] - xr[1]);
    if (t >= 2) s2 += fabsf(xr[0] - xr[2]);
    if (t >= 4) s4 += fabsf(xr[0] - xr[4]);
    if (t >= 6) s6 += fabsf(xr[0] - xr[6]);
}
// p1e[idx] for idx = k2*1536 + t*64 + i  (2 periods x 24 t x 64 hidden)
// R15 BUG was here: k2 split at 2048 (idx>>11) instead of 1536 -> k2=1,t<8
// never written (uninitialized LDS -> 1e16 garbage). (k2*24+t)*64+i == idx.
__device__ __forceinline__ void fill_p1e(float* p1e, int tid,
        const float* pe_w1, const float* pe_b1) {
    for (int idx = tid; idx < 3072; idx += 256) {
        int k2 = (idx >= 1536) ? 1 : 0;
        int rem = idx - k2 * 1536;
        int t = rem >> 6;
        int i = rem & 63;
        float period = (k2 == 0) ? 24.0f : 72.0f;
        float ph = 6.283185307179586f * (float)t / period;
        float v = sinf(ph) * pe_w1[(k2 * 2 + 0) * 64 + i]
                + cosf(ph) * pe_w1[(k2 * 2 + 1) * 64 + i] + pe_b1[k2 * 64 + i];
        p1e[idx] = gelu_f(v);
    }
}

// ==== A: lag+mean(768) + xhat(512) + prep_d(208) + ab_part(104) + w2e(256)
//         + per(1) + c1_per(13) + G(208)  -- grid 2070, 256 thr ====
__global__ void k_A(const float* __restrict__ x, const float* __restrict__ in_proj_w,
                    const float* __restrict__ in_proj_b, const float* __restrict__ noise_b,
                    const float* __restrict__ noise_w,
                    const float* __restrict__ pe_w1, const float* __restrict__ pe_b1,
                    const float* __restrict__ pe_w2, const float* __restrict__ pe_b2,
                    const float* __restrict__ sfe_w1, const float* __restrict__ sfe_b1,
                    const float* __restrict__ sfe_w2, const float* __restrict__ sfe_b2,
                    const float* __restrict__ comb_w1, const float* __restrict__ comb_w2,
                    float* __restrict__ ws) {
    __shared__ __align__(16) float smem[3400];
    int bx = blockIdx.x, tid = threadIdx.x;
    if (bx < 768) {
        // lag distances + spatial-mean partials (fused single x pass region)
        int t = bx % P_;
        int rb = bx / P_;
        int b = rb & 7, chunk = rb >> 3;
        const float* xp = x + (long)b * P_ * N_ * C_;
        float s1 = 0.f, s2 = 0.f, s4 = 0.f, s6 = 0.f;
        float4 msum = make_float4(0.f, 0.f, 0.f, 0.f);
        int idx4 = chunk * 1024 + tid;
        #pragma unroll
        for (int it = 0; it < 4; it++, idx4 += 256) {
            float4 xv[9];
            #pragma unroll
            for (int jj = 0; jj < 9; jj++)
                xv[jj] = (t - jj >= 0)
                    ? *(const float4*)&xp[(long)(t - jj) * (N_ * C_) + (idx4 << 2)]
                    : make_float4(0.f, 0.f, 0.f, 0.f);
            msum = f4add(msum, xv[0]);
            float xs0[9], xs1[9], xs2[9], xs3[9];
            #pragma unroll
            for (int jj = 0; jj < 9; jj++) {
                xs0[jj] = xv[jj].x; xs1[jj] = xv[jj].y;
                xs2[jj] = xv[jj].z; xs3[jj] = xv[jj].w;
            }
            lag_one(xs0, t, s1, s2, s4, s6);
            lag_one(xs1, t, s1, s2, s4, s6);
            lag_one(xs2, t, s1, s2, s4, s6);
            lag_one(xs3, t, s1, s2, s4, s6);
        }
        float4* red = (float4*)smem;
        red[tid] = make_float4(s1, s2, s4, s6);
        __syncthreads();
        for (int st = 128; st > 0; st >>= 1) {
            if (tid < st) red[tid] = f4add(red[tid], red[tid + st]);
            __syncthreads();
        }
        if (tid == 0) {
            ws[OFF_DLP + ((b * 4 + 0) * P_ + t) * 4 + chunk] = red[0].x;
            ws[OFF_DLP + ((b * 4 + 1) * P_ + t) * 4 + chunk] = red[0].y;
            ws[OFF_DLP + ((b * 4 + 2) * P_ + t) * 4 + chunk] = red[0].z;
            ws[OFF_DLP + ((b * 4 + 3) * P_ + t) * 4 + chunk] = red[0].w;
        }
        __syncthreads();
        red[tid] = msum;   // float4 covers c = (tid&3)*4 .. +3
        __syncthreads();
        for (int st = 128; st >= 4; st >>= 1) {
            if (tid < st) red[tid] = f4add(red[tid], red[tid + st]);
            __syncthreads();
        }
        if (tid < 16)
            ws[OFF_SMP + ((b * P_ + t) * 4 + chunk) * 16 + tid] = ((float*)red)[tid];
    } else if (bx < 1280) {
        // xhat DFT -> fragment-ordered xc
        int j = bx - 768;
        int ntile = j & 63, b = j >> 6;
        float* ct = smem;
        float* st = ct + K_ * P_;
        int n = ntile * 16 + (tid >> 4), c = tid & 15;
        for (int i = tid; i < K_ * P_; i += 256) {
            int k = i / P_, t = i % P_;
            int r = (k * t) % P_;
            float ph = 6.283185307179586f * (float)r / (float)P_;
            ct[i] = cosf(ph);
            st[i] = sinf(ph);
        }
        __syncthreads();
        float re[K_], im[K_];
        #pragma unroll
        for (int k = 0; k < K_; k++) { re[k] = 0.f; im[k] = 0.f; }
        for (int t = 0; t < P_; t++) {
            float v = x[((long)(b * P_ + t) * N_ + n) * C_ + c];
            #pragma unroll
            for (int k = 0; k < K_; k++) {
                re[k] += ct[k * P_ + t] * v;
                im[k] -= st[k * P_ + t] * v;
            }
        }
        ushort_t* xcp = (ushort_t*)(ws + OFF_XC);
        int nt32 = n >> 5, halfn = (n >> 4) & 1, l15n = n & 15;
        int lre = ((c >> 3) * 16 + l15n) * 8 + (c & 7);
        int lim = ((2 + (c >> 3)) * 16 + l15n) * 8 + (c & 7);
        #pragma unroll
        for (int k = 0; k < K_; k++) {
            long base = ((((long)(b * K_ + k) * 32 + nt32) * 2 + halfn) * 64) * 8;
            xcp[base + lre] = f2bf(re[k]);
            xcp[base + lim] = f2bf(im[k]);
        }
    } else if (bx < 1488) {
        // prep_d (16-wide K-steps) -> fragment-ordered Dt + BC
        int j = bx - 1280;
        int qt0 = (j & 3) * 64, it0 = ((j >> 2) & 3) * 64, k = j >> 4;
        float* As = smem;            // 64*17
        float* Bs = As + 64 * 17;    // 16*64
        int tq = tid & 15, ti = tid >> 4;
        float acc[4][4];
        #pragma unroll
        for (int r = 0; r < 4; r++)
            #pragma unroll
            for (int c = 0; c < 4; c++) acc[r][c] = 0.f;
        float bias = 0.f;
        for (int step = 0; step < 16; step++) {
            int ob = step * 16;
            __syncthreads();
            #pragma unroll
            for (int u = 0; u < 4; u++) {
                int idx = u * 256 + tid;
                int i = idx >> 4, o = idx & 15;
                As[i * 17 + o] = sfe_w2[((long)(k * 256 + it0 + i) << 8) + ob + o];
            }
            #pragma unroll
            for (int u = 0; u < 4; u++) {
                int idx = u * 256 + tid;
                int o = idx >> 6, q = idx & 63;
                Bs[o * 64 + q] = comb_w1[((long)(k * 256 + ob + o) << 8) + qt0 + q];
            }
            __syncthreads();
            if (it0 == 0 && tid < 64) {
                #pragma unroll
                for (int o = 0; o < 16; o++)
                    bias += sfe_b2[k * 256 + ob + o] * Bs[o * 64 + tid];
            }
            #pragma unroll 4
            for (int o = 0; o < 16; o++) {
                const float4 bv = *(const float4*)&Bs[o * 64 + tq * 4];
                float a[4];
                #pragma unroll
                for (int r = 0; r < 4; r++) a[r] = As[(ti * 4 + r) * 17 + o];
                #pragma unroll
                for (int r = 0; r < 4; r++) {
                    acc[r][0] += a[r] * bv.x;
                    acc[r][1] += a[r] * bv.y;
                    acc[r][2] += a[r] * bv.z;
                    acc[r][3] += a[r] * bv.w;
                }
            }
        }
        ushort_t* dtp = (ushort_t*)(ws + OFF_DD);
        #pragma unroll
        for (int c = 0; c < 4; c++)
            #pragma unroll
            for (int r = 0; r < 4; r++) {
                int q = qt0 + tq * 4 + c, i = it0 + ti * 4 + r;
                int wv = q >> 5, hf = (q >> 4) & 1, l = q & 15;
                int s = i >> 5, qd = (i >> 3) & 3, jj = i & 7;
                long idx = ((((long)(k * 8 + wv) * 8 + s) * 2 + hf) * 64 + qd * 16 + l) * 8 + jj;
                dtp[idx] = f2bf(acc[r][c]);
            }
        if (it0 == 0 && tid < 64)
            ws[OFF_BC + k * 256 + qt0 + tid] = bias;
    } else if (bx < 1592) {
        // ab_part
        int j = bx - 1488;
        int k = j >> 3, et = j & 7;
        int o = tid;
        float accA[C_], accB[C_];
        #pragma unroll
        for (int c = 0; c < C_; c++) { accA[c] = 0.f; accB[c] = 0.f; }
        const float* w1r = sfe_w1 + (long)k * 512 * 256;
        const float* w1i = w1r + 256 * 256;
        for (int e = et * 32; e < et * 32 + 32; e++) {
            float vr = w1r[e * 256 + o];
            float vi = w1i[e * 256 + o];
            #pragma unroll
            for (int c = 0; c < C_; c++) {
                float w = in_proj_w[c * 256 + e];
                accA[c] += w * vr;
                accB[c] += w * vi;
            }
        }
        float* abp = ws + OFF_ABP + (long)((k * 8 + et) * 32) * 256;
        #pragma unroll
        for (int c = 0; c < C_; c++) {
            abp[c * 256 + o] = accA[c];
            abp[(16 + c) * 256 + o] = accB[c];
        }
    } else if (bx < 1848) {
        // W2ext
        int q2 = bx - 1592;
        ushort_t* w2e = (ushort_t*)(ws + OFF_W2E);
        for (int i = tid; i < 288; i += 256) {
            float v = 0.f;
            if (i < 256) v = comb_w2[(i << 8) + q2];
            else if (i < 272) v = in_proj_w[((i - 256) << 8) + q2] * (1.0f / 0.3f);
            w2e[q2 * 288 + i] = f2bf(v);
        }
    } else if (bx < 1849) {
        // periodic [24][128] -> ws
        float* p1e = smem;   // 3072
        fill_p1e(p1e, tid, pe_w1, pe_b1);
        __syncthreads();
        for (int idx = tid; idx < 3072; idx += 256) {
            int t = idx >> 7, j = idx & 127;
            int k2 = j >> 6, jo = j & 63;
            float pv = pe_b2[k2 * 64 + jo];
            for (int i = 0; i < 64; i++)
                pv += p1e[(k2 * 24 + t) * 64 + i] * pe_w2[(k2 * 64 + i) * 64 + jo];
            ws[OFF_PER + t * 128 + j] = pv;
        }
    } else if (bx < 1862) {
        // c1_per[k][:]: DFT of periodic @ W1 + DC terms (self-contained)
        int k = bx - 1849;
        float* p1e = smem;           // 3072
        float* dre = p1e + 3072;     // 128
        float* dim = dre + 128;      // 128
        fill_p1e(p1e, tid, pe_w1, pe_b1);
        __syncthreads();
        {
            int j = tid & 127, half = tid >> 7;
            int k2 = j >> 6, jo = j & 63;
            float acc = 0.f;
            for (int t = 0; t < P_; t++) {
                float pv = pe_b2[k2 * 64 + jo];
                for (int i = 0; i < 64; i++)
                    pv += p1e[(k2 * 24 + t) * 64 + i] * pe_w2[(k2 * 64 + i) * 64 + jo];
                int r = (k * t) % P_;
                float ph = 6.283185307179586f * (float)r / (float)P_;
                acc += (half ? -sinf(ph) : cosf(ph)) * pv;
            }
            if (half) dim[j] = acc; else dre[j] = acc;
        }
        __syncthreads();
        int o = tid;
        const float* w1 = sfe_w1 + (long)k * 512 * 256;
        float acc = sfe_b1[k * 256 + o];
        for (int j = 0; j < 128; j++)
            acc += dre[j] * w1[j * 256 + o] + dim[j] * w1[(256 + j) * 256 + o];
        if (k == 0) {
            for (int c = 0; c < 256; c++) {
                float ipbe = in_proj_b[c] + ((c >= 128) ? noise_b[c - 128] : 0.f);
                acc += 24.0f * ipbe * w1[c * 256 + o];
            }
        }
        ws[OFF_C1PER + k * 256 + o] = acc;
    } else {
        // G[k][m][re/im][o] = noise_w[m][:] @ W1-noise-halves
        int j = bx - 1862;
        int k = j >> 4, m = j & 15;
        int o = tid;
        const float* w1 = sfe_w1 + (long)k * 512 * 256;
        float gre = 0.f, gim = 0.f;
        for (int c = 0; c < 128; c++) {
            float nw = noise_w[m * 128 + c];   // wave-uniform
            gre += nw * w1[(128 + c) * 256 + o];
            gim += nw * w1[(384 + c) * 256 + o];
        }
        ws[OFF_G + ((long)(k * 16 + m) * 2) * 256 + o] = gre;
        ws[OFF_G + ((long)(k * 16 + m) * 2 + 1) * 256 + o] = gim;
    }
}

// ==== B: gating + per-b scalars + c1 assembly (8 blocks) + ab_red (13), 256 thr ====
__global__ void k_B(const float* __restrict__ pool_param, const float* __restrict__ in_proj_b,
                    const float* __restrict__ noise_w, const float* __restrict__ noise_b,
                    float* __restrict__ ws, float* __restrict__ out) {
    __shared__ float d[96], ad[96], med[4], mad[4], attb[24], sml[384],
                     asml[16], msml[16], dsr[208], dsi[208];
    int bx = blockIdx.x, tid = threadIdx.x;
    if (bx < 8) {
        int b = bx;
        if (tid < 96) {
            const float* dp = ws + OFF_DLP + (b * 96 + tid) * 4;
            d[tid] = (dp[0] + dp[1] + dp[2] + dp[3]) * (1.0f / (N_ * C_));
        }
        __syncthreads();
        if (tid < 96) {
            int li = tid / P_, t = tid - li * P_;
            float v = d[tid];
            int rank = 0;
            #pragma unroll
            for (int jj = 0; jj < P_; jj++) {
                float dj = d[li * P_ + jj];
                rank += (dj < v || (dj == v && jj < t)) ? 1 : 0;
            }
            if (rank == 11) med[li] = v;
        }
        __syncthreads();
        if (tid < 96) ad[tid] = fabsf(d[tid] - med[tid / P_]);
        __syncthreads();
        if (tid < 96) {
            int li = tid / P_, t = tid - li * P_;
            float v = ad[tid];
            int rank = 0;
            #pragma unroll
            for (int jj = 0; jj < P_; jj++) {
                float dj = ad[li * P_ + jj];
                rank += (dj < v || (dj == v && jj < t)) ? 1 : 0;
            }
            if (rank == 11) mad[li] = v;
        }
        __syncthreads();
        if (tid < 96) {
            int li = tid / P_;
            float z = (d[tid] - med[li]) / (mad[li] * 1.4826f + 1e-6f);
            ad[tid] = softplus_f(z);
        }
        __syncthreads();
        if (tid == 0) {
            float g[P_], gbuf[P_];
            #pragma unroll
            for (int tt = 0; tt < P_; tt++)
                g[tt] = 0.25f * (ad[tt] + ad[P_ + tt] + ad[2 * P_ + tt] + ad[3 * P_ + tt]);
            float c = g[0];
            gbuf[0] = g[0];
            for (int tt = 1; tt < P_; tt++) { c = 0.6f * c + 0.4f * g[tt]; gbuf[tt] = c; }
            float mean = 0.f;
            for (int tt = 0; tt < P_; tt++) mean += gbuf[tt];
            mean *= (1.0f / P_);
            float gate[P_];
            #pragma unroll
            for (int tt = 0; tt < P_; tt++) gate[tt] = 1.0f / (1.0f + expf(-1.5f * (gbuf[tt] - mean)));
            float m = -1e30f;
            float pp[P_];
            #pragma unroll
            for (int tt = 0; tt < P_; tt++) { pp[tt] = pool_param[tt]; m = fmaxf(m, pp[tt]); }
            float ssum = 0.f;
            #pragma unroll
            for (int tt = 0; tt < P_; tt++) { pp[tt] = expf(pp[tt] - m); ssum += pp[tt]; }
            float m2 = -1e30f;
            #pragma unroll
            for (int tt = 0; tt < P_; tt++) { pp[tt] = (pp[tt] / ssum) * (1.0f + gate[tt]); m2 = fmaxf(m2, pp[tt]); }
            float s2 = 0.f;
            #pragma unroll
            for (int tt = 0; tt < P_; tt++) { pp[tt] = expf(pp[tt] - m2); s2 += pp[tt]; }
            #pragma unroll
            for (int tt = 0; tt < P_; tt++) attb[tt] = pp[tt] / s2;
        }
        __syncthreads();
        if (tid < K_) {
            int k = tid;
            float cre = 0.f, cim = 0.f;
            for (int t2 = 0; t2 < P_; t2++) {
                int r = (k * t2) % P_;
                float ph = 6.283185307179586f * (float)r / (float)P_;
                float a = attb[t2];
                cre += a * cosf(ph);
                cim += a * sinf(ph);
            }
            float w = (k == 0 || k == 12) ? 1.0f : 2.0f;
            ws[OFF_GAM + b * 32 + k] = (w / 24.0f) * cre;
            ws[OFF_GAM + b * 32 + 16 + k] = -(w / 24.0f) * cim;
        }
        for (int i = tid; i < 384; i += 256) {
            int t = i >> 4, m = i & 15;
            const float* sp = ws + OFF_SMP + ((b * P_ + t) * 4) * 16 + m;
            sml[i] = (sp[0] + sp[16] + sp[32] + sp[48]) * (1.0f / 1024.0f);
        }
        __syncthreads();
        if (tid < 16) {
            float sa = 0.f, sm_ = 0.f;
            for (int t = 0; t < P_; t++) {
                sa += attb[t] * sml[t * 16 + tid];
                sm_ += sml[t * 16 + tid];
            }
            asml[tid] = sa;
            msml[tid] = sm_ * (1.0f / P_);
        }
        if (tid < 208) {
            int k = tid >> 4, m = tid & 15;
            float re = 0.f, im = 0.f;
            for (int t = 0; t < P_; t++) {
                int r = (k * t) % P_;
                float ph = 6.283185307179586f * (float)r / (float)P_;
                float v = sml[t * 16 + m];
                re += cosf(ph) * v;
                im -= sinf(ph) * v;
            }
            dsr[tid] = re;
            dsi[tid] = im;
        }
        __syncthreads();
        {
            int o = tid;
            float zv, tv;
            if (o < 128) {
                float sa = 0.f, sm_ = 0.f;
                for (int t = 0; t < P_; t++) {
                    float pv = ws[OFF_PER + t * 128 + o];
                    sa += attb[t] * pv;
                    sm_ += pv;
                }
                zv = in_proj_b[o] + sa;
                tv = sm_ * (1.0f / P_);
            } else {
                int cc = o - 128;
                float nz = 0.f, nm = 0.f;
                for (int m = 0; m < 16; m++) {
                    float nw = noise_w[m * 128 + cc];
                    nz += asml[m] * nw;
                    nm += msml[m] * nw;
                }
                zv = in_proj_b[o] + noise_b[cc] + nz;
                tv = noise_b[cc] + nm;
            }
            ws[OFF_ZWC + b * 256 + o] = zv;
            out[2097152 + b * 256 + o] = tv;
        }
        {
            int o = tid;
            for (int k = 0; k < K_; k++) {
                float acc = ws[OFF_C1PER + k * 256 + o];
                const float* gp = ws + OFF_G + ((long)(k * 16) * 2) * 256 + o;
                #pragma unroll
                for (int m = 0; m < 16; m++)
                    acc += dsr[k * 16 + m] * gp[(m * 2) * 256]
                         + dsi[k * 16 + m] * gp[(m * 2 + 1) * 256];
                ws[OFF_C1 + (b * K_ + k) * 256 + o] = acc;
            }
        }
    } else {
        // ab_red -> ABt fragment order
        int k = bx - 8, o = tid;
        ushort_t* abt = (ushort_t*)(ws + OFF_AB);
        const float* base = ws + OFF_ABP + (long)(k * 8 * 32) * 256;
        int wv = o >> 5, hf = (o >> 4) & 1, l = o & 15;
        long obase = (((long)(k * 8 + wv) * 2 + hf) * 64) * 8;
        #pragma unroll
        for (int ch = 0; ch < 32; ch++) {
            float s = 0.f;
            #pragma unroll
            for (int et = 0; et < 8; et++) s += base[(et * 32 + ch) * 256 + o];
            abt[obase + ((ch >> 3) * 16 + l) * 8 + (ch & 7)] = f2bf(s);
        }
    }
}

// pack-stage: coalesced fragment loads + p-MFMA + gelu-pack (c1 direct, 2 loads)
__device__ __forceinline__ void pack_stage(
        const float* __restrict__ ws, const ushort_t* __restrict__ xch,
        const ushort_t* __restrict__ abt, int b, int kk, int ntile,
        int wave, int lane, int oc0, int oc1, ushort4_t* w) {
    const ushort_t* xb = xch + (((long)(b * K_ + kk) * 32 + ntile) * 2) * 512 + lane * 8;
    bf16x8 pa0 = *(const bf16x8*)xb;
    bf16x8 pa1 = *(const bf16x8*)(xb + 512);
    const ushort_t* ab = abt + ((long)(kk * 8 + wave) * 2) * 512 + lane * 8;
    bf16x8 pb0 = *(const bf16x8*)ab;
    bf16x8 pb1 = *(const bf16x8*)(ab + 512);
    const float* cp = ws + OFF_C1 + (long)(b * K_ + kk) * 256;
    float4 c10 = *(const float4*)&cp[oc0];
    float4 c11 = *(const float4*)&cp[oc1];
    f32x4 p00 = {}, p01 = {}, p10 = {}, p11 = {};
    p00 = __builtin_amdgcn_mfma_f32_16x16x32_bf16(pb0, pa0, p00, 0, 0, 0);
    p01 = __builtin_amdgcn_mfma_f32_16x16x32_bf16(pb0, pa1, p01, 0, 0, 0);
    p10 = __builtin_amdgcn_mfma_f32_16x16x32_bf16(pb1, pa0, p10, 0, 0, 0);
    p11 = __builtin_amdgcn_mfma_f32_16x16x32_bf16(pb1, pa1, p11, 0, 0, 0);
    w[0] = pack4(p00, c10);
    w[1] = pack4(p01, c10);
    w[2] = pack4(p10, c11);
    w[3] = pack4(p11, c11);
}

// ==== F1x: split-k(2) GEMM1 partial (512 blocks) + xw (256 blocks), 512 thr ====
__global__ __launch_bounds__(512, 4) void k_final1(
        const float* __restrict__ ws, const ushort_t* __restrict__ xch,
        const ushort_t* __restrict__ abt, float* __restrict__ pacc,
        float* __restrict__ xwout) {
    __shared__ ushort_t sl[32 * 264];    // 16896 B
    int bx = blockIdx.x, tid = threadIdx.x;
    if (bx < 512) {
        int ntile = bx & 31, b = (bx >> 5) & 7, kh = bx >> 8;
        const int k0 = kh ? 7 : 0;
        const int k1 = kh ? K_ : 7;
        int lane = tid & 63, wave = tid >> 6;
        int l15 = lane & 15, quad = lane >> 4;
        int wq0 = wave * 32;
        const ushort_t* dt = (const ushort_t*)(ws + OFF_DD);
        int oc0 = wq0 + quad * 4, oc1 = oc0 + 16;
        f32x4 a00 = {}, a01 = {}, a10 = {}, a11 = {};
        ushort4_t w[4];
        pack_stage(ws, xch, abt, b, k0, ntile, wave, lane, oc0, oc1, w);
        for (int k = k0; k < k1; k++) {
            __syncthreads();
            *(ushort4_t*)&sl[l15 * 264 + oc0] = w[0];
            *(ushort4_t*)&sl[(16 + l15) * 264 + oc0] = w[1];
            *(ushort4_t*)&sl[l15 * 264 + oc1] = w[2];
            *(ushort4_t*)&sl[(16 + l15) * 264 + oc1] = w[3];
            __syncthreads();
            if (k + 1 < k1)
                pack_stage(ws, xch, abt, b, k + 1, ntile, wave, lane, oc0, oc1, w);
            const ushort_t* dwb = dt + ((long)(k * 8 + wave) * 16) * 512 + lane * 8;
            #pragma unroll
            for (int s = 0; s < 8; s++) {
                int i0 = s * 32 + quad * 8;
                bf16x8 A0 = *(const bf16x8*)(dwb + s * 1024);
                bf16x8 A1 = *(const bf16x8*)(dwb + s * 1024 + 512);
                bf16x8 B0 = *(const bf16x8*)&sl[l15 * 264 + i0];
                bf16x8 B1 = *(const bf16x8*)&sl[(16 + l15) * 264 + i0];
                a00 = __builtin_amdgcn_mfma_f32_16x16x32_bf16(A0, B0, a00, 0, 0, 0);
                a01 = __builtin_amdgcn_mfma_f32_16x16x32_bf16(A0, B1, a01, 0, 0, 0);
                a10 = __builtin_amdgcn_mfma_f32_16x16x32_bf16(A1, B0, a10, 0, 0, 0);
                a11 = __builtin_amdgcn_mfma_f32_16x16x32_bf16(A1, B1, a11, 0, 0, 0);
            }
        }
        float* pp = pacc + ((((long)(kh * 8 + b) * 32 + ntile) * 8 + wave) * 4) * 256 + lane * 4;
        *(float4*)(pp + 0)   = make_float4(a00[0], a00[1], a00[2], a00[3]);
        *(float4*)(pp + 256) = make_float4(a01[0], a01[1], a01[2], a01[3]);
        *(float4*)(pp + 512) = make_float4(a10[0], a10[1], a10[2], a10[3]);
        *(float4*)(pp + 768) = make_float4(a11[0], a11[1], a11[2], a11[3]);
    } else {
        // xw from fragment-ordered xc (gamma inverse-DFT)
        int j = bx - 512;
        int b = j >> 5, n0 = (j & 31) * 32;
        int n = n0 + (tid >> 4), c = tid & 15;
        float gre[K_], gim[K_];
        #pragma unroll
        for (int k = 0; k < K_; k++) {
            gre[k] = ws[OFF_GAM + b * 32 + k];
            gim[k] = ws[OFF_GAM + b * 32 + 16 + k];
        }
        const ushort_t* xcp = (const ushort_t*)(ws + OFF_XC);
        int nt32 = n >> 5, halfn = (n >> 4) & 1, l15n = n & 15;
        int lre = ((c >> 3) * 16 + l15n) * 8 + (c & 7);
        int lim = ((2 + (c >> 3)) * 16 + l15n) * 8 + (c & 7);
        float acc = 0.f;
        #pragma unroll
        for (int k = 0; k < K_; k++) {
            long base = ((((long)(b * K_ + k) * 32 + nt32) * 2 + halfn) * 64) * 8;
            acc += gre[k] * bf2f(xcp[base + lre]) + gim[k] * bf2f(xcp[base + lim]);
        }
        xwout[((long)b * N_ + n) * C_ + c] = acc;
    }
}

// ==== F2: sum 2 partials -> bias+gelu -> GEMM2 -> z, 32n tile ====
__global__ __launch_bounds__(512, 2) void k_final2(
        const float* __restrict__ ws, const float* __restrict__ pacc,
        const float* __restrict__ comb_b1, const float* __restrict__ comb_b2,
        float* __restrict__ out) {
    int ntile = blockIdx.x, b = blockIdx.y;  // 32 x 8
    int n0 = ntile * 32;
    int tid = threadIdx.x;
    int lane = tid & 63, wave = tid >> 6;
    int l15 = lane & 15, quad = lane >> 4;
    int wq0 = wave * 32;
    __shared__ ushort_t sh2[32 * 296];
    const ushort_t* w2e = (const ushort_t*)(ws + OFF_W2E);
    int oc0 = wq0 + quad * 4, oc1 = oc0 + 16;
    const float* p0 = pacc + ((((long)(0 * 8 + b) * 32 + ntile) * 8 + wave) * 4) * 256 + lane * 4;
    const float* p1 = pacc + ((((long)(1 * 8 + b) * 32 + ntile) * 8 + wave) * 4) * 256 + lane * 4;
    float4 s00 = f4add(*(const float4*)(p0 + 0),   *(const float4*)(p1 + 0));
    float4 s01 = f4add(*(const float4*)(p0 + 256), *(const float4*)(p1 + 256));
    float4 s10 = f4add(*(const float4*)(p0 + 512), *(const float4*)(p1 + 512));
    float4 s11 = f4add(*(const float4*)(p0 + 768), *(const float4*)(p1 + 768));
    float4 bc0 = *(const float4*)&comb_b1[oc0];
    float4 bc1 = *(const float4*)&comb_b1[oc1];
    #pragma unroll
    for (int k = 0; k < K_; k++) {
        bc0 = f4add(bc0, *(const float4*)&ws[OFF_BC + k * 256 + oc0]);
        bc1 = f4add(bc1, *(const float4*)&ws[OFF_BC + k * 256 + oc1]);
    }
    *(ushort4_t*)&sh2[l15 * 296 + oc0]        = pack4f(s00, bc0);
    *(ushort4_t*)&sh2[(16 + l15) * 296 + oc0] = pack4f(s01, bc0);
    *(ushort4_t*)&sh2[l15 * 296 + oc1]        = pack4f(s10, bc1);
    *(ushort4_t*)&sh2[(16 + l15) * 296 + oc1] = pack4f(s11, bc1);
    {
        int row = tid >> 4, cc = tid & 15;
        float xv = ws[OFF_XW + ((long)b * N_ + n0 + row) * C_ + cc];
        sh2[row * 296 + 256 + cc] = f2bf(xv);
        sh2[row * 296 + 272 + cc] = 0;
    }
    __syncthreads();
    f32x4 h00 = {}, h01 = {}, h10 = {}, h11 = {};
    #pragma unroll
    for (int s = 0; s < 9; s++) {
        int i0 = s * 32 + quad * 8;
        bf16x8 A0 = *(const bf16x8*)&w2e[(wq0 + l15) * 288 + i0];
        bf16x8 A1 = *(const bf16x8*)&w2e[(wq0 + 16 + l15) * 288 + i0];
        bf16x8 B0 = *(const bf16x8*)&sh2[l15 * 296 + i0];
        bf16x8 B1 = *(const bf16x8*)&sh2[(16 + l15) * 296 + i0];
        h00 = __builtin_amdgcn_mfma_f32_16x16x32_bf16(A0, B0, h00, 0, 0, 0);
        h01 = __builtin_amdgcn_mfma_f32_16x16x32_bf16(A0, B1, h01, 0, 0, 0);
        h10 = __builtin_amdgcn_mfma_f32_16x16x32_bf16(A1, B0, h10, 0, 0, 0);
        h11 = __builtin_amdgcn_mfma_f32_16x16x32_bf16(A1, B1, h11, 0, 0, 0);
    }
    float4 zc0 = *(const float4*)&ws[OFF_ZWC + b * 256 + oc0];
    float4 zc1 = *(const float4*)&ws[OFF_ZWC + b * 256 + oc1];
    float4 cb0 = *(const float4*)&comb_b2[oc0];
    float4 cb1 = *(const float4*)&comb_b2[oc1];
    long ob = ((long)b * N_ + n0) << 8;
    float4 o00, o01, o10, o11;
    o00.x = zc0.x + 0.3f * (h00[0] + cb0.x); o00.y = zc0.y + 0.3f * (h00[1] + cb0.y);
    o00.z = zc0.z + 0.3f * (h00[2] + cb0.z); o00.w = zc0.w + 0.3f * (h00[3] + cb0.w);
    o01.x = zc0.x + 0.3f * (h01[0] + cb0.x); o01.y = zc0.y + 0.3f * (h01[1] + cb0.y);
    o01.z = zc0.z + 0.3f * (h01[2] + cb0.z); o01.w = zc0.w + 0.3f * (h01[3] + cb0.w);
    o10.x = zc1.x + 0.3f * (h10[0] + cb1.x); o10.y = zc1.y + 0.3f * (h10[1] + cb1.y);
    o10.z = zc1.z + 0.3f * (h10[2] + cb1.z); o10.w = zc1.w + 0.3f * (h10[3] + cb1.w);
    o11.x = zc1.x + 0.3f * (h11[0] + cb1.x); o11.y = zc1.y + 0.3f * (h11[1] + cb1.y);
    o11.z = zc1.z + 0.3f * (h11[2] + cb1.z); o11.w = zc1.w + 0.3f * (h11[3] + cb1.w);
    *(float4*)&out[ob + ((long)l15 << 8) + oc0] = o00;
    *(float4*)&out[ob + ((long)(16 + l15) << 8) + oc0] = o01;
    *(float4*)&out[ob + ((long)l15 << 8) + oc1] = o10;
    *(float4*)&out[ob + ((long)(16 + l15) << 8) + oc1] = o11;
}

extern "C" void kernel_launch(void* const* d_in, const int* in_sizes, int n_in,
                              void* d_out, int out_size, void* d_ws, size_t ws_size,
                              hipStream_t stream) {
    const float* x = (const float*)d_in[0];
    const float* in_proj_w = (const float*)d_in[1];
    const float* in_proj_b = (const float*)d_in[2];
    const float* pe_w1 = (const float*)d_in[3];
    const float* pe_b1 = (const float*)d_in[4];
    const float* pe_w2 = (const float*)d_in[5];
    const float* pe_b2 = (const float*)d_in[6];
    const float* noise_w = (const float*)d_in[7];
    const float* noise_b = (const float*)d_in[8];
    const float* sfe_w1 = (const float*)d_in[9];
    const float* sfe_b1 = (const float*)d_in[10];
    const float* sfe_w2 = (const float*)d_in[11];
    const float* sfe_b2 = (const float*)d_in[12];
    const float* comb_w1 = (const float*)d_in[13];
    const float* comb_b1 = (const float*)d_in[14];
    const float* comb_w2 = (const float*)d_in[15];
    const float* comb_b2 = (const float*)d_in[16];
    const float* pool_param = (const float*)d_in[17];
    float* ws = (float*)d_ws;
    float* out = (float*)d_out;

    hipLaunchKernelGGL(k_A, dim3(2070), dim3(256), 0, stream,
                       x, in_proj_w, in_proj_b, noise_b, noise_w,
                       pe_w1, pe_b1, pe_w2, pe_b2,
                       sfe_w1, sfe_b1, sfe_w2, sfe_b2, comb_w1, comb_w2, ws);
    hipLaunchKernelGGL(k_B, dim3(21), dim3(256), 0, stream,
                       pool_param, in_proj_b, noise_w, noise_b, ws, out);
    hipLaunchKernelGGL(k_final1, dim3(768), dim3(512), 0, stream,
                       ws, (const ushort_t*)(ws + OFF_XC), (const ushort_t*)(ws + OFF_AB),
                       ws + OFF_PACC, ws + OFF_XW);
    hipLaunchKernelGGL(k_final2, dim3(32, 8), dim3(512), 0, stream,
                       ws, ws + OFF_PACC, comb_b1, comb_b2, out);
}